// Round 8
// baseline (725.626 us; speedup 1.0000x reference)
//
#include <hip/hip_runtime.h>

#define Snum 2048
#define SCALE 0.08838834764831845f

typedef __attribute__((ext_vector_type(8))) __bf16 bf16x8;
typedef __attribute__((ext_vector_type(4))) float f32x4;
typedef __attribute__((ext_vector_type(16))) float f32x16;

__device__ inline unsigned short f2bf(float f) {
    unsigned int u = __float_as_uint(f);
    unsigned int r = u + 0x7FFFu + ((u >> 16) & 1u);
    return (unsigned short)(r >> 16);
}
__device__ inline float bf2f(unsigned short u) {
    return __uint_as_float(((unsigned)u) << 16);
}
__device__ inline void gld_lds16(const unsigned short* g, unsigned short* l) {
    __builtin_amdgcn_global_load_lds(
        (const __attribute__((address_space(1))) unsigned int*)g,
        (__attribute__((address_space(3))) unsigned int*)l, 16, 0, 0);
}

// ---------------- weight prep: Wv cast, W1/Wk/Wq transposes ----------------
__global__ __launch_bounds__(256) void prep_weights(
    const float* __restrict__ Wv, unsigned short* __restrict__ Wvbf,   // [768][512] cast only
    const float* __restrict__ W1, unsigned short* __restrict__ W1t,    // [256][512]
    const float* __restrict__ Wk, const float* __restrict__ Wq,
    unsigned short* __restrict__ Wqkt)                                  // [256][768]
{
    const int id = blockIdx.x;
    if (id < 384) {
        const int base = (id * 256 + threadIdx.x) * 4;
        const float4 v = *(const float4*)(Wv + base);
        ushort4 o;
        o.x = f2bf(v.x); o.y = f2bf(v.y); o.z = f2bf(v.z); o.w = f2bf(v.w);
        *(ushort4*)(Wvbf + base) = o;
        return;
    }
    __shared__ float t[32][33];
    const float* in; unsigned short* out; int K, N, bx, by;
    if (id < 512)      { int q = id - 384; in = W1; out = W1t;  K = 512; N = 256; bx = q & 7; by = q >> 3; }
    else if (id < 608) { int q = id - 512; in = Wk; out = Wqkt; K = 768; N = 128; bx = q & 3; by = q >> 2; }
    else               { int q = id - 608; in = Wq; out = Wqkt + (size_t)128 * 768; K = 768; N = 128; bx = q & 3; by = q >> 2; }

    const int tx = threadIdx.x & 31, ty = threadIdx.x >> 5;
    #pragma unroll
    for (int i = 0; i < 4; ++i) {
        int k = by * 32 + ty + i * 8, n = bx * 32 + tx;
        t[ty + i * 8][tx] = in[(size_t)k * N + n];
    }
    __syncthreads();
    #pragma unroll
    for (int i = 0; i < 4; ++i) {
        int n = bx * 32 + ty + i * 8, k = by * 32 + tx;
        out[(size_t)n * K + k] = f2bf(t[tx][ty + i * 8]);
    }
}

// ---------------- Gt = W1t @ Wvbf^T  (48 blocks) + bias_prime (block 48) ----------------
__global__ __launch_bounds__(256) void gt_bias(
    const unsigned short* __restrict__ W1t,   // [256][512]
    const unsigned short* __restrict__ Wvbf,  // [768][512]
    const float* __restrict__ bv, const float* __restrict__ b1,
    unsigned short* __restrict__ Gtb,         // [256][768]
    float* __restrict__ bp)                   // [256]
{
    if (blockIdx.x == 48) {
        const int n = threadIdx.x;
        float s = b1[n];
        const unsigned short* row = W1t + (size_t)n * 512;
        for (int h = 0; h < 512; h += 8) {
            uint4 u = *(const uint4*)(row + h);
            const unsigned short* v = (const unsigned short*)&u;
            #pragma unroll
            for (int i = 0; i < 8; ++i) s += bv[h + i] * bf2f(v[i]);
        }
        bp[n] = s;
        return;
    }
    __shared__ __align__(16) unsigned short As[2][64 * 32];
    __shared__ __align__(16) unsigned short Bs[2][64 * 32];
    const int tid = threadIdx.x;
    const int bn = blockIdx.x % 12, bm = blockIdx.x / 12;
    const int wid = tid >> 6, lane = tid & 63;
    const int wm = (wid >> 1) * 32, wn = (wid & 1) * 32;
    const int lr = lane & 15, g = lane >> 4;
    const int r0 = bm * 64, c0 = bn * 64;
    const int K = 512, NT = 16, N = 768;
    const int srow = lane >> 2, skc = (lane & 3) * 8;

    f32x4 acc[2][2] = {};

    gld_lds16(W1t  + (size_t)(r0 + wid * 16 + srow) * K + skc, &As[0][wid * 16 * 32]);
    gld_lds16(Wvbf + (size_t)(c0 + wid * 16 + srow) * K + skc, &Bs[0][wid * 16 * 32]);
    __syncthreads();

    for (int t = 0; t < NT; ++t) {
        const int cur = t & 1, nxt = cur ^ 1;
        if (t + 1 < NT) {
            const int k0 = (t + 1) * 32;
            gld_lds16(W1t  + (size_t)(r0 + wid * 16 + srow) * K + k0 + skc, &As[nxt][wid * 16 * 32]);
            gld_lds16(Wvbf + (size_t)(c0 + wid * 16 + srow) * K + k0 + skc, &Bs[nxt][wid * 16 * 32]);
        }
        bf16x8 aF[2], bF[2];
        #pragma unroll
        for (int mm = 0; mm < 2; ++mm) aF[mm] = *(const bf16x8*)&As[cur][(wm + mm * 16 + lr) * 32 + g * 8];
        #pragma unroll
        for (int nn = 0; nn < 2; ++nn) bF[nn] = *(const bf16x8*)&Bs[cur][(wn + nn * 16 + lr) * 32 + g * 8];
        #pragma unroll
        for (int mm = 0; mm < 2; ++mm)
            #pragma unroll
            for (int nn = 0; nn < 2; ++nn)
                acc[mm][nn] = __builtin_amdgcn_mfma_f32_16x16x32_bf16(bF[nn], aF[mm], acc[mm][nn], 0, 0, 0);
        __syncthreads();
    }

    #pragma unroll
    for (int mm = 0; mm < 2; ++mm)
        #pragma unroll
        for (int nn = 0; nn < 2; ++nn) {
            const int orow = r0 + wm + mm * 16 + lr;
            const int colb = c0 + wn + nn * 16 + g * 4;
            unsigned short o[4];
            #pragma unroll
            for (int reg = 0; reg < 4; ++reg) o[reg] = f2bf(acc[mm][nn][reg]);
            *(ushort4*)&Gtb[(size_t)orow * N + colb] = *(ushort4*)o;
        }
}

// ---------------- proj_qk: one pass over x -> Kall = relu(x@Wk+bk), Pq = x@Wq ----------------
__global__ __launch_bounds__(256) void proj_qk(
    const float* __restrict__ x, const unsigned short* __restrict__ Bt,
    const float* __restrict__ bk,
    unsigned short* __restrict__ Kall,   // [49152][128] bf16
    unsigned short* __restrict__ Pq)     // [49152][128] bf16
{
    __shared__ __align__(16) unsigned short As[2][64 * 32];
    __shared__ __align__(16) unsigned short Bs[2][256 * 32];
    const int tid = threadIdx.x;
    const int wid = tid >> 6, lane = tid & 63;
    const int wn = wid * 64;
    const int lr = lane & 15, g = lane >> 4;
    const int r0 = blockIdx.x * 64;
    const int K = 768, NT = 24;

    const int arow = tid >> 2, akc = (tid & 3) * 8;

    f32x4 acc[4][4] = {};

    float4 a0 = *(const float4*)(x + (size_t)(r0 + arow) * K + akc);
    float4 a1 = *(const float4*)(x + (size_t)(r0 + arow) * K + akc + 4);
    {
        unsigned short v[8];
        v[0] = f2bf(a0.x); v[1] = f2bf(a0.y); v[2] = f2bf(a0.z); v[3] = f2bf(a0.w);
        v[4] = f2bf(a1.x); v[5] = f2bf(a1.y); v[6] = f2bf(a1.z); v[7] = f2bf(a1.w);
        *(uint4*)&As[0][arow * 32 + akc] = *(uint4*)v;
    }
    #pragma unroll
    for (int c = 0; c < 4; ++c) {
        const int rr = wid * 64 + c * 16;
        gld_lds16(Bt + (size_t)(rr + (lane >> 2)) * K + (lane & 3) * 8, &Bs[0][rr * 32]);
    }
    __syncthreads();

    for (int t = 0; t < NT; ++t) {
        const int cur = t & 1, nxt = cur ^ 1;
        if (t + 1 < NT) {
            const int k0 = (t + 1) * 32;
            a0 = *(const float4*)(x + (size_t)(r0 + arow) * K + k0 + akc);
            a1 = *(const float4*)(x + (size_t)(r0 + arow) * K + k0 + akc + 4);
            #pragma unroll
            for (int c = 0; c < 4; ++c) {
                const int rr = wid * 64 + c * 16;
                gld_lds16(Bt + (size_t)(rr + (lane >> 2)) * K + k0 + (lane & 3) * 8,
                          &Bs[nxt][rr * 32]);
            }
        }

        bf16x8 aF[4], bF[4];
        #pragma unroll
        for (int mm = 0; mm < 4; ++mm) aF[mm] = *(const bf16x8*)&As[cur][(mm * 16 + lr) * 32 + g * 8];
        #pragma unroll
        for (int nn = 0; nn < 4; ++nn) bF[nn] = *(const bf16x8*)&Bs[cur][(wn + nn * 16 + lr) * 32 + g * 8];
        #pragma unroll
        for (int mm = 0; mm < 4; ++mm)
            #pragma unroll
            for (int nn = 0; nn < 4; ++nn)
                acc[mm][nn] = __builtin_amdgcn_mfma_f32_16x16x32_bf16(bF[nn], aF[mm], acc[mm][nn], 0, 0, 0);

        if (t + 1 < NT) {
            unsigned short v[8];
            v[0] = f2bf(a0.x); v[1] = f2bf(a0.y); v[2] = f2bf(a0.z); v[3] = f2bf(a0.w);
            v[4] = f2bf(a1.x); v[5] = f2bf(a1.y); v[6] = f2bf(a1.z); v[7] = f2bf(a1.w);
            *(uint4*)&As[nxt][arow * 32 + akc] = *(uint4*)v;
        }
        __syncthreads();
    }

    #pragma unroll
    for (int mm = 0; mm < 4; ++mm)
        #pragma unroll
        for (int nn = 0; nn < 4; ++nn) {
            const int row = r0 + mm * 16 + lr;
            const int colb = wn + nn * 16 + g * 4;
            unsigned short o[4];
            if (colb < 128) {
                #pragma unroll
                for (int reg = 0; reg < 4; ++reg) {
                    float kv = acc[mm][nn][reg] + bk[colb + reg];
                    o[reg] = f2bf(kv > 0.f ? kv : 0.f);
                }
                *(ushort4*)&Kall[(size_t)row * 128 + colb] = *(ushort4*)o;
            } else {
                #pragma unroll
                for (int reg = 0; reg < 4; ++reg) o[reg] = f2bf(acc[mm][nn][reg]);
                *(ushort4*)&Pq[(size_t)row * 128 + (colb - 128)] = *(ushort4*)o;
            }
        }
}

// ---------------- scores + softmax + hbar, with W2 transpose blocks riding along ----------------
__global__ __launch_bounds__(256) void scores_plus_w2t(
    const float* __restrict__ x,
    const unsigned short* __restrict__ Pq,
    const float* __restrict__ bq,
    const unsigned short* __restrict__ Kall,
    unsigned short* __restrict__ hbar,
    const float* __restrict__ W2, unsigned short* __restrict__ W2t)
{
    if (blockIdx.x >= 1024) {
        __shared__ float t[32][33];
        const int id = blockIdx.x - 1024;
        const int bx = id >> 3, by = id & 7;
        const int tx = threadIdx.x & 31, ty = threadIdx.x >> 5;
        #pragma unroll
        for (int i = 0; i < 4; ++i) {
            int k = by * 32 + ty + i * 8, n = bx * 32 + tx;
            t[ty + i * 8][tx] = W2[(size_t)k * 32000 + n];
        }
        __syncthreads();
        #pragma unroll
        for (int i = 0; i < 4; ++i) {
            int n = bx * 32 + ty + i * 8, k = by * 32 + tx;
            W2t[(size_t)n * 256 + k] = f2bf(t[tx][ty + i * 8]);
        }
        return;
    }

    const int wid = threadIdx.x >> 6, lane = threadIdx.x & 63;
    const int r = blockIdx.x * 4 + wid;
    const int b = r >> 11, s = r & 2047;

    float qa = 0.f, qb_ = 0.f;
    #pragma unroll
    for (int l = 0; l < 12; ++l) {
        const unsigned short* prow = Pq + ((size_t)(l * 2 + b) * Snum + s) * 128 + lane * 2;
        unsigned int u = *(const unsigned int*)prow;
        qa += bf2f((unsigned short)(u & 0xFFFF));
        qb_ += bf2f((unsigned short)(u >> 16));
    }
    float q0 = qa * (1.0f / 12.0f) + bq[lane * 2];
    float q1 = qb_ * (1.0f / 12.0f) + bq[lane * 2 + 1];
    q0 = q0 > 0.f ? q0 : 0.f;
    q1 = q1 > 0.f ? q1 : 0.f;
    q0 = bf2f(f2bf(q0)); q1 = bf2f(f2bf(q1));

    float sc[12];
    #pragma unroll
    for (int l = 0; l < 12; ++l) {
        const unsigned short* krow = Kall + ((size_t)(l * 2 + b) * Snum + s) * 128 + lane * 2;
        unsigned int u = *(const unsigned int*)krow;
        float p = q0 * bf2f((unsigned short)(u & 0xFFFF)) + q1 * bf2f((unsigned short)(u >> 16));
        #pragma unroll
        for (int off = 32; off > 0; off >>= 1) p += __shfl_xor(p, off, 64);
        sc[l] = p * SCALE;
    }
    float m = sc[0];
    #pragma unroll
    for (int l = 1; l < 12; ++l) m = fmaxf(m, sc[l]);
    float att[12], den = 0.f;
    #pragma unroll
    for (int l = 0; l < 12; ++l) { att[l] = __expf(sc[l] - m); den += att[l]; }
    const float inv = 1.0f / den;
    #pragma unroll
    for (int l = 0; l < 12; ++l) att[l] *= inv;

    #pragma unroll
    for (int jv = 0; jv < 3; ++jv) {
        const int d0 = jv * 256 + lane * 4;
        float a0 = 0.f, a1 = 0.f, a2 = 0.f, a3 = 0.f;
        #pragma unroll
        for (int l = 0; l < 12; ++l) {
            const float4 v = *(const float4*)(x + ((size_t)(l * 2 + b) * Snum + s) * 768 + d0);
            a0 += att[l] * v.x; a1 += att[l] * v.y; a2 += att[l] * v.z; a3 += att[l] * v.w;
        }
        ushort4 o;
        o.x = f2bf(a0); o.y = f2bf(a1); o.z = f2bf(a2); o.w = f2bf(a3);
        *(ushort4*)(hbar + (size_t)r * 768 + d0) = o;
    }
}

// ---------------- 64x64 bf16 MFMA GEMM, dbuf gld_lds staging, swapped epilogue ----------------
template <int RELU, int OUT_BF16, int BIAS>
__global__ __launch_bounds__(256) void gemm64(
    const unsigned short* __restrict__ A, const unsigned short* __restrict__ Bt,
    const float* __restrict__ bias, void* __restrict__ out, int M, int N, int K)
{
    __shared__ __align__(16) unsigned short As[2][64 * 32];
    __shared__ __align__(16) unsigned short Bs[2][64 * 32];
    const int tid = threadIdx.x;
    const int bn = blockIdx.x, bm = blockIdx.y;
    const int wid = tid >> 6, lane = tid & 63;
    const int wm = (wid >> 1) * 32, wn = (wid & 1) * 32;
    const int lr = lane & 15, g = lane >> 4;
    const int r0 = bm * 64, c0 = bn * 64;
    const int NT = K / 32;

    const int srow = lane >> 2, skc = (lane & 3) * 8;

    f32x4 acc[2][2] = {};

    gld_lds16(A  + (size_t)(r0 + wid * 16 + srow) * K + skc, &As[0][wid * 16 * 32]);
    gld_lds16(Bt + (size_t)(c0 + wid * 16 + srow) * K + skc, &Bs[0][wid * 16 * 32]);
    __syncthreads();

    for (int t = 0; t < NT; ++t) {
        const int cur = t & 1, nxt = cur ^ 1;
        if (t + 1 < NT) {
            const int k0 = (t + 1) * 32;
            gld_lds16(A  + (size_t)(r0 + wid * 16 + srow) * K + k0 + skc, &As[nxt][wid * 16 * 32]);
            gld_lds16(Bt + (size_t)(c0 + wid * 16 + srow) * K + k0 + skc, &Bs[nxt][wid * 16 * 32]);
        }

        bf16x8 aF[2], bF[2];
        #pragma unroll
        for (int mm = 0; mm < 2; ++mm) aF[mm] = *(const bf16x8*)&As[cur][(wm + mm * 16 + lr) * 32 + g * 8];
        #pragma unroll
        for (int nn = 0; nn < 2; ++nn) bF[nn] = *(const bf16x8*)&Bs[cur][(wn + nn * 16 + lr) * 32 + g * 8];
        #pragma unroll
        for (int mm = 0; mm < 2; ++mm)
            #pragma unroll
            for (int nn = 0; nn < 2; ++nn)
                acc[mm][nn] = __builtin_amdgcn_mfma_f32_16x16x32_bf16(bF[nn], aF[mm], acc[mm][nn], 0, 0, 0);
        __syncthreads();
    }

    #pragma unroll
    for (int mm = 0; mm < 2; ++mm)
        #pragma unroll
        for (int nn = 0; nn < 2; ++nn) {
            const int orow = r0 + wm + mm * 16 + lr;
            const int colb = c0 + wn + nn * 16 + g * 4;
            float vr[4];
            #pragma unroll
            for (int reg = 0; reg < 4; ++reg) {
                float v = acc[mm][nn][reg] + (BIAS ? bias[colb + reg] : 0.f);
                vr[reg] = (RELU && v < 0.f) ? 0.f : v;
            }
            if (OUT_BF16) {
                unsigned short o[4];
                #pragma unroll
                for (int reg = 0; reg < 4; ++reg) o[reg] = f2bf(vr[reg]);
                *(ushort4*)&((unsigned short*)out)[(size_t)orow * N + colb] = *(ushort4*)o;
            } else {
                *(float4*)&((float*)out)[(size_t)orow * N + colb] = *(float4*)vr;
            }
        }
}

// ---------------- final GEMM: 32x32x16 fragments, 128x128 tile, BK=32 dbuf, nt stores ----------------
// M=4096, N=32000, K=256. Grid 8000, XCD-swizzled.
__global__ __launch_bounds__(256) void gemm_out(
    const unsigned short* __restrict__ A,   // [4096][256] bf16
    const unsigned short* __restrict__ Bt,  // [32000][256] bf16
    const float* __restrict__ bias, float* __restrict__ out)
{
    __shared__ __align__(16) unsigned short As[2][128 * 32];  // 2 x 8 KB
    __shared__ __align__(16) unsigned short Bs[2][128 * 32];
    const int K = 256, N = 32000, NT = 8;
    const int orig = blockIdx.x;
    const int swz = (orig & 7) * 1000 + (orig >> 3);
    const int bn = swz >> 5, bm = swz & 31;
    const int tid = threadIdx.x;
    const int wid = tid >> 6, lane = tid & 63;
    const int wm = (wid >> 1) * 64, wn = (wid & 1) * 64;
    const int l31 = lane & 31, hi = lane >> 5;
    const int r0 = bm * 128, c0 = bn * 128;

    f32x16 acc[2][2] = {};

    #pragma unroll
    for (int c = 0; c < 2; ++c) {
        const int rr = wid * 32 + c * 16;
        gld_lds16(A  + (size_t)(r0 + rr + (lane >> 2)) * K + (lane & 3) * 8, &As[0][rr * 32]);
        gld_lds16(Bt + (size_t)(c0 + rr + (lane >> 2)) * K + (lane & 3) * 8, &Bs[0][rr * 32]);
    }
    __syncthreads();

    for (int t = 0; t < NT; ++t) {
        const int cur = t & 1, nxt = cur ^ 1;
        if (t + 1 < NT) {
            const int k0 = (t + 1) * 32;
            #pragma unroll
            for (int c = 0; c < 2; ++c) {
                const int rr = wid * 32 + c * 16;
                gld_lds16(A  + (size_t)(r0 + rr + (lane >> 2)) * K + k0 + (lane & 3) * 8, &As[nxt][rr * 32]);
                gld_lds16(Bt + (size_t)(c0 + rr + (lane >> 2)) * K + k0 + (lane & 3) * 8, &Bs[nxt][rr * 32]);
            }
        }

        // 32x32x16 fragments: lane holds row=l31, k = ksub*16 + hi*8 + e
        #pragma unroll
        for (int ksub = 0; ksub < 2; ++ksub) {
            bf16x8 aF[2], bF[2];
            #pragma unroll
            for (int mm = 0; mm < 2; ++mm)
                aF[mm] = *(const bf16x8*)&As[cur][(wm + mm * 32 + l31) * 32 + ksub * 16 + hi * 8];
            #pragma unroll
            for (int nn = 0; nn < 2; ++nn)
                bF[nn] = *(const bf16x8*)&Bs[cur][(wn + nn * 32 + l31) * 32 + ksub * 16 + hi * 8];
            #pragma unroll
            for (int mm = 0; mm < 2; ++mm)
                #pragma unroll
                for (int nn = 0; nn < 2; ++nn)
                    acc[mm][nn] = __builtin_amdgcn_mfma_f32_32x32x16_bf16(bF[nn], aF[mm], acc[mm][nn], 0, 0, 0);
        }
        __syncthreads();
    }

    // swapped 32x32 epilogue: lane owns M-row = l31; cols = nn*32 + q*8 + hi*4 + (0..3)
    #pragma unroll
    for (int mm = 0; mm < 2; ++mm)
        #pragma unroll
        for (int nn = 0; nn < 2; ++nn) {
            const int row = r0 + wm + mm * 32 + l31;
            #pragma unroll
            for (int q = 0; q < 4; ++q) {
                const int colb = c0 + wn + nn * 32 + q * 8 + hi * 4;
                const float4 b4 = *(const float4*)&bias[colb];
                f32x4 o;
                o[0] = acc[mm][nn][q * 4 + 0] + b4.x;
                o[1] = acc[mm][nn][q * 4 + 1] + b4.y;
                o[2] = acc[mm][nn][q * 4 + 2] + b4.z;
                o[3] = acc[mm][nn][q * 4 + 3] + b4.w;
                __builtin_nontemporal_store(o, (f32x4*)&out[(size_t)row * N + colb]);
            }
        }
}

extern "C" void kernel_launch(void* const* d_in, const int* in_sizes, int n_in,
                              void* d_out, int out_size, void* d_ws, size_t ws_size,
                              hipStream_t stream) {
    (void)in_sizes; (void)n_in; (void)out_size; (void)ws_size;

    const float* x  = (const float*)d_in[0];
    const float* Wq = (const float*)d_in[1];
    const float* bq = (const float*)d_in[2];
    const float* Wk = (const float*)d_in[3];
    const float* bk = (const float*)d_in[4];
    const float* Wv = (const float*)d_in[5];
    const float* bv = (const float*)d_in[6];
    const float* W1 = (const float*)d_in[7];
    const float* b1 = (const float*)d_in[8];
    const float* W2 = (const float*)d_in[9];
    const float* b2 = (const float*)d_in[10];

    char* p = (char*)d_ws;
    unsigned short* Wqkt  = (unsigned short*)p; p += (size_t)256 * 768 * 2;
    unsigned short* Wvbf  = (unsigned short*)p; p += (size_t)768 * 512 * 2;
    unsigned short* W1t   = (unsigned short*)p; p += (size_t)256 * 512 * 2;
    unsigned short* Gtb   = (unsigned short*)p; p += (size_t)256 * 768 * 2;
    float*          bprim = (float*)p;          p += (size_t)256 * 4;
    unsigned short* W2t   = (unsigned short*)p; p += (size_t)32000 * 256 * 2;
    unsigned short* Kall  = (unsigned short*)p; p += (size_t)49152 * 128 * 2;
    unsigned short* Pq    = (unsigned short*)p; p += (size_t)49152 * 128 * 2;
    unsigned short* hbar  = (unsigned short*)p; p += (size_t)4096 * 768 * 2;
    unsigned short* midb  = (unsigned short*)p; p += (size_t)4096 * 256 * 2;

    // weight prep: Wv cast, W1t, Wqkt
    prep_weights<<<dim3(704), dim3(256), 0, stream>>>(Wv, Wvbf, W1, W1t, Wk, Wq, Wqkt);

    // Gt = (Wv@W1)^T and b' = bv@W1 + b1, one launch
    gt_bias<<<dim3(49), dim3(256), 0, stream>>>(W1t, Wvbf, bv, b1, Gtb, bprim);

    // one pass over x: Kall = relu(x@Wk+bk), Pq = x@Wq
    proj_qk<<<dim3(49152 / 64), dim3(256), 0, stream>>>(x, Wqkt, bk, Kall, Pq);

    // scores (q fused) -> softmax -> hbar; W2 transpose rides along
    scores_plus_w2t<<<dim3(1024 + 8000), dim3(256), 0, stream>>>(
        x, Pq, bq, Kall, hbar, W2, W2t);

    // mid = relu(hbar @ Gt^T + b')
    gemm64<1, 1, 1><<<dim3(256 / 64, 4096 / 64), dim3(256), 0, stream>>>(
        hbar, Gtb, bprim, midb, 4096, 256, 768);

    // out = mid @ W2 + b2  (fp32)
    gemm_out<<<dim3(8000), dim3(256), 0, stream>>>(midb, W2t, b2, (float*)d_out);
}

// Round 9
// 371.238 us; speedup vs baseline: 1.9546x; 1.9546x over previous
//
#include <hip/hip_runtime.h>

#define Snum 2048
#define SCALE 0.08838834764831845f

typedef __attribute__((ext_vector_type(8))) __bf16 bf16x8;
typedef __attribute__((ext_vector_type(4))) float f32x4;

__device__ inline unsigned short f2bf(float f) {
    unsigned int u = __float_as_uint(f);
    unsigned int r = u + 0x7FFFu + ((u >> 16) & 1u);
    return (unsigned short)(r >> 16);
}
__device__ inline float bf2f(unsigned short u) {
    return __uint_as_float(((unsigned)u) << 16);
}
__device__ inline void gld_lds16(const unsigned short* g, unsigned short* l) {
    __builtin_amdgcn_global_load_lds(
        (const __attribute__((address_space(1))) unsigned int*)g,
        (__attribute__((address_space(3))) unsigned int*)l, 16, 0, 0);
}

// ---------------- weight prep: Wv cast, W1/Wk/Wq transposes ----------------
__global__ __launch_bounds__(256) void prep_weights(
    const float* __restrict__ Wv, unsigned short* __restrict__ Wvbf,   // [768][512] cast only
    const float* __restrict__ W1, unsigned short* __restrict__ W1t,    // [256][512]
    const float* __restrict__ Wk, const float* __restrict__ Wq,
    unsigned short* __restrict__ Wqkt)                                  // [256][768]
{
    const int id = blockIdx.x;
    if (id < 384) {
        const int base = (id * 256 + threadIdx.x) * 4;
        const float4 v = *(const float4*)(Wv + base);
        ushort4 o;
        o.x = f2bf(v.x); o.y = f2bf(v.y); o.z = f2bf(v.z); o.w = f2bf(v.w);
        *(ushort4*)(Wvbf + base) = o;
        return;
    }
    __shared__ float t[32][33];
    const float* in; unsigned short* out; int K, N, bx, by;
    if (id < 512)      { int q = id - 384; in = W1; out = W1t;  K = 512; N = 256; bx = q & 7; by = q >> 3; }
    else if (id < 608) { int q = id - 512; in = Wk; out = Wqkt; K = 768; N = 128; bx = q & 3; by = q >> 2; }
    else               { int q = id - 608; in = Wq; out = Wqkt + (size_t)128 * 768; K = 768; N = 128; bx = q & 3; by = q >> 2; }

    const int tx = threadIdx.x & 31, ty = threadIdx.x >> 5;
    #pragma unroll
    for (int i = 0; i < 4; ++i) {
        int k = by * 32 + ty + i * 8, n = bx * 32 + tx;
        t[ty + i * 8][tx] = in[(size_t)k * N + n];
    }
    __syncthreads();
    #pragma unroll
    for (int i = 0; i < 4; ++i) {
        int n = bx * 32 + ty + i * 8, k = by * 32 + tx;
        out[(size_t)n * K + k] = f2bf(t[tx][ty + i * 8]);
    }
}

// ---------------- Gt = W1t @ Wvbf^T  (48 blocks) + bias_prime (block 48) ----------------
__global__ __launch_bounds__(256) void gt_bias(
    const unsigned short* __restrict__ W1t,   // [256][512]
    const unsigned short* __restrict__ Wvbf,  // [768][512]
    const float* __restrict__ bv, const float* __restrict__ b1,
    unsigned short* __restrict__ Gtb,         // [256][768]
    float* __restrict__ bp)                   // [256]
{
    if (blockIdx.x == 48) {
        const int n = threadIdx.x;
        float s = b1[n];
        const unsigned short* row = W1t + (size_t)n * 512;
        for (int h = 0; h < 512; h += 8) {
            uint4 u = *(const uint4*)(row + h);
            const unsigned short* v = (const unsigned short*)&u;
            #pragma unroll
            for (int i = 0; i < 8; ++i) s += bv[h + i] * bf2f(v[i]);
        }
        bp[n] = s;
        return;
    }
    __shared__ __align__(16) unsigned short As[2][64 * 32];
    __shared__ __align__(16) unsigned short Bs[2][64 * 32];
    const int tid = threadIdx.x;
    const int bn = blockIdx.x % 12, bm = blockIdx.x / 12;
    const int wid = tid >> 6, lane = tid & 63;
    const int wm = (wid >> 1) * 32, wn = (wid & 1) * 32;
    const int lr = lane & 15, g = lane >> 4;
    const int r0 = bm * 64, c0 = bn * 64;
    const int K = 512, NT = 16, N = 768;
    const int srow = lane >> 2, skc = (lane & 3) * 8;

    f32x4 acc[2][2] = {};

    gld_lds16(W1t  + (size_t)(r0 + wid * 16 + srow) * K + skc, &As[0][wid * 16 * 32]);
    gld_lds16(Wvbf + (size_t)(c0 + wid * 16 + srow) * K + skc, &Bs[0][wid * 16 * 32]);
    __syncthreads();

    for (int t = 0; t < NT; ++t) {
        const int cur = t & 1, nxt = cur ^ 1;
        if (t + 1 < NT) {
            const int k0 = (t + 1) * 32;
            gld_lds16(W1t  + (size_t)(r0 + wid * 16 + srow) * K + k0 + skc, &As[nxt][wid * 16 * 32]);
            gld_lds16(Wvbf + (size_t)(c0 + wid * 16 + srow) * K + k0 + skc, &Bs[nxt][wid * 16 * 32]);
        }
        bf16x8 aF[2], bF[2];
        #pragma unroll
        for (int mm = 0; mm < 2; ++mm) aF[mm] = *(const bf16x8*)&As[cur][(wm + mm * 16 + lr) * 32 + g * 8];
        #pragma unroll
        for (int nn = 0; nn < 2; ++nn) bF[nn] = *(const bf16x8*)&Bs[cur][(wn + nn * 16 + lr) * 32 + g * 8];
        #pragma unroll
        for (int mm = 0; mm < 2; ++mm)
            #pragma unroll
            for (int nn = 0; nn < 2; ++nn)
                acc[mm][nn] = __builtin_amdgcn_mfma_f32_16x16x32_bf16(bF[nn], aF[mm], acc[mm][nn], 0, 0, 0);
        __syncthreads();
    }

    #pragma unroll
    for (int mm = 0; mm < 2; ++mm)
        #pragma unroll
        for (int nn = 0; nn < 2; ++nn) {
            const int orow = r0 + wm + mm * 16 + lr;
            const int colb = c0 + wn + nn * 16 + g * 4;
            unsigned short o[4];
            #pragma unroll
            for (int reg = 0; reg < 4; ++reg) o[reg] = f2bf(acc[mm][nn][reg]);
            *(ushort4*)&Gtb[(size_t)orow * N + colb] = *(ushort4*)o;
        }
}

// ---------------- proj_qk: one pass over x -> Kall = relu(x@Wk+bk), Pq = x@Wq ----------------
__global__ __launch_bounds__(256) void proj_qk(
    const float* __restrict__ x, const unsigned short* __restrict__ Bt,
    const float* __restrict__ bk,
    unsigned short* __restrict__ Kall,   // [49152][128] bf16
    unsigned short* __restrict__ Pq)     // [49152][128] bf16
{
    __shared__ __align__(16) unsigned short As[2][64 * 32];
    __shared__ __align__(16) unsigned short Bs[2][256 * 32];
    const int tid = threadIdx.x;
    const int wid = tid >> 6, lane = tid & 63;
    const int wn = wid * 64;
    const int lr = lane & 15, g = lane >> 4;
    const int r0 = blockIdx.x * 64;
    const int K = 768, NT = 24;

    const int arow = tid >> 2, akc = (tid & 3) * 8;

    f32x4 acc[4][4] = {};

    float4 a0 = *(const float4*)(x + (size_t)(r0 + arow) * K + akc);
    float4 a1 = *(const float4*)(x + (size_t)(r0 + arow) * K + akc + 4);
    {
        unsigned short v[8];
        v[0] = f2bf(a0.x); v[1] = f2bf(a0.y); v[2] = f2bf(a0.z); v[3] = f2bf(a0.w);
        v[4] = f2bf(a1.x); v[5] = f2bf(a1.y); v[6] = f2bf(a1.z); v[7] = f2bf(a1.w);
        *(uint4*)&As[0][arow * 32 + akc] = *(uint4*)v;
    }
    #pragma unroll
    for (int c = 0; c < 4; ++c) {
        const int rr = wid * 64 + c * 16;
        gld_lds16(Bt + (size_t)(rr + (lane >> 2)) * K + (lane & 3) * 8, &Bs[0][rr * 32]);
    }
    __syncthreads();

    for (int t = 0; t < NT; ++t) {
        const int cur = t & 1, nxt = cur ^ 1;
        if (t + 1 < NT) {
            const int k0 = (t + 1) * 32;
            a0 = *(const float4*)(x + (size_t)(r0 + arow) * K + k0 + akc);
            a1 = *(const float4*)(x + (size_t)(r0 + arow) * K + k0 + akc + 4);
            #pragma unroll
            for (int c = 0; c < 4; ++c) {
                const int rr = wid * 64 + c * 16;
                gld_lds16(Bt + (size_t)(rr + (lane >> 2)) * K + k0 + (lane & 3) * 8,
                          &Bs[nxt][rr * 32]);
            }
        }

        bf16x8 aF[4], bF[4];
        #pragma unroll
        for (int mm = 0; mm < 4; ++mm) aF[mm] = *(const bf16x8*)&As[cur][(mm * 16 + lr) * 32 + g * 8];
        #pragma unroll
        for (int nn = 0; nn < 4; ++nn) bF[nn] = *(const bf16x8*)&Bs[cur][(wn + nn * 16 + lr) * 32 + g * 8];
        #pragma unroll
        for (int mm = 0; mm < 4; ++mm)
            #pragma unroll
            for (int nn = 0; nn < 4; ++nn)
                acc[mm][nn] = __builtin_amdgcn_mfma_f32_16x16x32_bf16(bF[nn], aF[mm], acc[mm][nn], 0, 0, 0);

        if (t + 1 < NT) {
            unsigned short v[8];
            v[0] = f2bf(a0.x); v[1] = f2bf(a0.y); v[2] = f2bf(a0.z); v[3] = f2bf(a0.w);
            v[4] = f2bf(a1.x); v[5] = f2bf(a1.y); v[6] = f2bf(a1.z); v[7] = f2bf(a1.w);
            *(uint4*)&As[nxt][arow * 32 + akc] = *(uint4*)v;
        }
        __syncthreads();
    }

    #pragma unroll
    for (int mm = 0; mm < 4; ++mm)
        #pragma unroll
        for (int nn = 0; nn < 4; ++nn) {
            const int row = r0 + mm * 16 + lr;
            const int colb = wn + nn * 16 + g * 4;
            unsigned short o[4];
            if (colb < 128) {
                #pragma unroll
                for (int reg = 0; reg < 4; ++reg) {
                    float kv = acc[mm][nn][reg] + bk[colb + reg];
                    o[reg] = f2bf(kv > 0.f ? kv : 0.f);
                }
                *(ushort4*)&Kall[(size_t)row * 128 + colb] = *(ushort4*)o;
            } else {
                #pragma unroll
                for (int reg = 0; reg < 4; ++reg) o[reg] = f2bf(acc[mm][nn][reg]);
                *(ushort4*)&Pq[(size_t)row * 128 + (colb - 128)] = *(ushort4*)o;
            }
        }
}

// ---------------- scores + softmax + hbar, with W2 transpose blocks riding along ----------------
__global__ __launch_bounds__(256) void scores_plus_w2t(
    const float* __restrict__ x,
    const unsigned short* __restrict__ Pq,
    const float* __restrict__ bq,
    const unsigned short* __restrict__ Kall,
    unsigned short* __restrict__ hbar,
    const float* __restrict__ W2, unsigned short* __restrict__ W2t)
{
    if (blockIdx.x >= 1024) {
        __shared__ float t[32][33];
        const int id = blockIdx.x - 1024;
        const int bx = id >> 3, by = id & 7;
        const int tx = threadIdx.x & 31, ty = threadIdx.x >> 5;
        #pragma unroll
        for (int i = 0; i < 4; ++i) {
            int k = by * 32 + ty + i * 8, n = bx * 32 + tx;
            t[ty + i * 8][tx] = W2[(size_t)k * 32000 + n];
        }
        __syncthreads();
        #pragma unroll
        for (int i = 0; i < 4; ++i) {
            int n = bx * 32 + ty + i * 8, k = by * 32 + tx;
            W2t[(size_t)n * 256 + k] = f2bf(t[tx][ty + i * 8]);
        }
        return;
    }

    const int wid = threadIdx.x >> 6, lane = threadIdx.x & 63;
    const int r = blockIdx.x * 4 + wid;
    const int b = r >> 11, s = r & 2047;

    float qa = 0.f, qb_ = 0.f;
    #pragma unroll
    for (int l = 0; l < 12; ++l) {
        const unsigned short* prow = Pq + ((size_t)(l * 2 + b) * Snum + s) * 128 + lane * 2;
        unsigned int u = *(const unsigned int*)prow;
        qa += bf2f((unsigned short)(u & 0xFFFF));
        qb_ += bf2f((unsigned short)(u >> 16));
    }
    float q0 = qa * (1.0f / 12.0f) + bq[lane * 2];
    float q1 = qb_ * (1.0f / 12.0f) + bq[lane * 2 + 1];
    q0 = q0 > 0.f ? q0 : 0.f;
    q1 = q1 > 0.f ? q1 : 0.f;
    q0 = bf2f(f2bf(q0)); q1 = bf2f(f2bf(q1));

    float sc[12];
    #pragma unroll
    for (int l = 0; l < 12; ++l) {
        const unsigned short* krow = Kall + ((size_t)(l * 2 + b) * Snum + s) * 128 + lane * 2;
        unsigned int u = *(const unsigned int*)krow;
        float p = q0 * bf2f((unsigned short)(u & 0xFFFF)) + q1 * bf2f((unsigned short)(u >> 16));
        #pragma unroll
        for (int off = 32; off > 0; off >>= 1) p += __shfl_xor(p, off, 64);
        sc[l] = p * SCALE;
    }
    float m = sc[0];
    #pragma unroll
    for (int l = 1; l < 12; ++l) m = fmaxf(m, sc[l]);
    float att[12], den = 0.f;
    #pragma unroll
    for (int l = 0; l < 12; ++l) { att[l] = __expf(sc[l] - m); den += att[l]; }
    const float inv = 1.0f / den;
    #pragma unroll
    for (int l = 0; l < 12; ++l) att[l] *= inv;

    #pragma unroll
    for (int jv = 0; jv < 3; ++jv) {
        const int d0 = jv * 256 + lane * 4;
        float a0 = 0.f, a1 = 0.f, a2 = 0.f, a3 = 0.f;
        #pragma unroll
        for (int l = 0; l < 12; ++l) {
            const float4 v = *(const float4*)(x + ((size_t)(l * 2 + b) * Snum + s) * 768 + d0);
            a0 += att[l] * v.x; a1 += att[l] * v.y; a2 += att[l] * v.z; a3 += att[l] * v.w;
        }
        ushort4 o;
        o.x = f2bf(a0); o.y = f2bf(a1); o.z = f2bf(a2); o.w = f2bf(a3);
        *(ushort4*)(hbar + (size_t)r * 768 + d0) = o;
    }
}

// ---------------- 64x64 bf16 MFMA GEMM, dbuf gld_lds staging, swapped epilogue ----------------
template <int RELU, int OUT_BF16, int BIAS>
__global__ __launch_bounds__(256) void gemm64(
    const unsigned short* __restrict__ A, const unsigned short* __restrict__ Bt,
    const float* __restrict__ bias, void* __restrict__ out, int M, int N, int K)
{
    __shared__ __align__(16) unsigned short As[2][64 * 32];
    __shared__ __align__(16) unsigned short Bs[2][64 * 32];
    const int tid = threadIdx.x;
    const int bn = blockIdx.x, bm = blockIdx.y;
    const int wid = tid >> 6, lane = tid & 63;
    const int wm = (wid >> 1) * 32, wn = (wid & 1) * 32;
    const int lr = lane & 15, g = lane >> 4;
    const int r0 = bm * 64, c0 = bn * 64;
    const int NT = K / 32;

    const int srow = lane >> 2, skc = (lane & 3) * 8;

    f32x4 acc[2][2] = {};

    gld_lds16(A  + (size_t)(r0 + wid * 16 + srow) * K + skc, &As[0][wid * 16 * 32]);
    gld_lds16(Bt + (size_t)(c0 + wid * 16 + srow) * K + skc, &Bs[0][wid * 16 * 32]);
    __syncthreads();

    for (int t = 0; t < NT; ++t) {
        const int cur = t & 1, nxt = cur ^ 1;
        if (t + 1 < NT) {
            const int k0 = (t + 1) * 32;
            gld_lds16(A  + (size_t)(r0 + wid * 16 + srow) * K + k0 + skc, &As[nxt][wid * 16 * 32]);
            gld_lds16(Bt + (size_t)(c0 + wid * 16 + srow) * K + k0 + skc, &Bs[nxt][wid * 16 * 32]);
        }

        bf16x8 aF[2], bF[2];
        #pragma unroll
        for (int mm = 0; mm < 2; ++mm) aF[mm] = *(const bf16x8*)&As[cur][(wm + mm * 16 + lr) * 32 + g * 8];
        #pragma unroll
        for (int nn = 0; nn < 2; ++nn) bF[nn] = *(const bf16x8*)&Bs[cur][(wn + nn * 16 + lr) * 32 + g * 8];
        #pragma unroll
        for (int mm = 0; mm < 2; ++mm)
            #pragma unroll
            for (int nn = 0; nn < 2; ++nn)
                acc[mm][nn] = __builtin_amdgcn_mfma_f32_16x16x32_bf16(bF[nn], aF[mm], acc[mm][nn], 0, 0, 0);
        __syncthreads();
    }

    #pragma unroll
    for (int mm = 0; mm < 2; ++mm)
        #pragma unroll
        for (int nn = 0; nn < 2; ++nn) {
            const int orow = r0 + wm + mm * 16 + lr;
            const int colb = c0 + wn + nn * 16 + g * 4;
            float vr[4];
            #pragma unroll
            for (int reg = 0; reg < 4; ++reg) {
                float v = acc[mm][nn][reg] + (BIAS ? bias[colb + reg] : 0.f);
                vr[reg] = (RELU && v < 0.f) ? 0.f : v;
            }
            if (OUT_BF16) {
                unsigned short o[4];
                #pragma unroll
                for (int reg = 0; reg < 4; ++reg) o[reg] = f2bf(vr[reg]);
                *(ushort4*)&((unsigned short*)out)[(size_t)orow * N + colb] = *(ushort4*)o;
            } else {
                *(float4*)&((float*)out)[(size_t)orow * N + colb] = *(float4*)vr;
            }
        }
}

// ---------------- final GEMM: direct-from-L2 register GEMM (no LDS, no barriers) ----------------
// out = mid @ W2t^T + b2. M=4096, N=32000, K=256. Grid 8000, XCD-swizzled.
// A (2 MB) and per-XCD B working set (~2 MB) are L2-resident -> no LDS staging needed.
__global__ __launch_bounds__(256) void gemm_out(
    const unsigned short* __restrict__ A,   // [4096][256] bf16
    const unsigned short* __restrict__ Bt,  // [32000][256] bf16
    const float* __restrict__ bias, float* __restrict__ out)
{
    const int K = 256, N = 32000;
    const int orig = blockIdx.x;
    const int swz = (orig & 7) * 1000 + (orig >> 3);
    const int bn = swz >> 5, bm = swz & 31;
    const int tid = threadIdx.x;
    const int wid = tid >> 6, lane = tid & 63;
    const int wm = (wid >> 1) * 64, wn = (wid & 1) * 64;
    const int lr = lane & 15, g = lane >> 4;
    const int r0 = bm * 128, c0 = bn * 128;

    f32x4 acc[4][4] = {};

    // per-lane fragment base pointers (16x16x32: row = tile + mm*16 + lr, k = k0 + g*8)
    const unsigned short* Ab = A  + (size_t)(r0 + wm + lr) * K + g * 8;
    const unsigned short* Bb = Bt + (size_t)(c0 + wn + lr) * K + g * 8;

    #pragma unroll
    for (int t = 0; t < 8; ++t) {
        const int k0 = t * 32;
        bf16x8 aF[4], bF[4];
        #pragma unroll
        for (int mm = 0; mm < 4; ++mm) aF[mm] = *(const bf16x8*)(Ab + (size_t)(mm * 16) * K + k0);
        #pragma unroll
        for (int nn = 0; nn < 4; ++nn) bF[nn] = *(const bf16x8*)(Bb + (size_t)(nn * 16) * K + k0);
        #pragma unroll
        for (int mm = 0; mm < 4; ++mm)
            #pragma unroll
            for (int nn = 0; nn < 4; ++nn)
                acc[mm][nn] = __builtin_amdgcn_mfma_f32_16x16x32_bf16(bF[nn], aF[mm], acc[mm][nn], 0, 0, 0);
    }

    // swapped epilogue: lane owns row = lr, 4 consecutive cols (full 64B sector per row per instr)
    #pragma unroll
    for (int mm = 0; mm < 4; ++mm)
        #pragma unroll
        for (int nn = 0; nn < 4; ++nn) {
            const int row = r0 + wm + mm * 16 + lr;
            const int colb = c0 + wn + nn * 16 + g * 4;
            const float4 b4 = *(const float4*)&bias[colb];
            f32x4 o = acc[mm][nn];
            o[0] += b4.x; o[1] += b4.y; o[2] += b4.z; o[3] += b4.w;
            __builtin_nontemporal_store(o, (f32x4*)&out[(size_t)row * N + colb]);
        }
}

extern "C" void kernel_launch(void* const* d_in, const int* in_sizes, int n_in,
                              void* d_out, int out_size, void* d_ws, size_t ws_size,
                              hipStream_t stream) {
    (void)in_sizes; (void)n_in; (void)out_size; (void)ws_size;

    const float* x  = (const float*)d_in[0];
    const float* Wq = (const float*)d_in[1];
    const float* bq = (const float*)d_in[2];
    const float* Wk = (const float*)d_in[3];
    const float* bk = (const float*)d_in[4];
    const float* Wv = (const float*)d_in[5];
    const float* bv = (const float*)d_in[6];
    const float* W1 = (const float*)d_in[7];
    const float* b1 = (const float*)d_in[8];
    const float* W2 = (const float*)d_in[9];
    const float* b2 = (const float*)d_in[10];

    char* p = (char*)d_ws;
    unsigned short* Wqkt  = (unsigned short*)p; p += (size_t)256 * 768 * 2;
    unsigned short* Wvbf  = (unsigned short*)p; p += (size_t)768 * 512 * 2;
    unsigned short* W1t   = (unsigned short*)p; p += (size_t)256 * 512 * 2;
    unsigned short* Gtb   = (unsigned short*)p; p += (size_t)256 * 768 * 2;
    float*          bprim = (float*)p;          p += (size_t)256 * 4;
    unsigned short* W2t   = (unsigned short*)p; p += (size_t)32000 * 256 * 2;
    unsigned short* Kall  = (unsigned short*)p; p += (size_t)49152 * 128 * 2;
    unsigned short* Pq    = (unsigned short*)p; p += (size_t)49152 * 128 * 2;
    unsigned short* hbar  = (unsigned short*)p; p += (size_t)4096 * 768 * 2;
    unsigned short* midb  = (unsigned short*)p; p += (size_t)4096 * 256 * 2;

    // weight prep: Wv cast, W1t, Wqkt
    prep_weights<<<dim3(704), dim3(256), 0, stream>>>(Wv, Wvbf, W1, W1t, Wk, Wq, Wqkt);

    // Gt = (Wv@W1)^T and b' = bv@W1 + b1, one launch
    gt_bias<<<dim3(49), dim3(256), 0, stream>>>(W1t, Wvbf, bv, b1, Gtb, bprim);

    // one pass over x: Kall = relu(x@Wk+bk), Pq = x@Wq
    proj_qk<<<dim3(49152 / 64), dim3(256), 0, stream>>>(x, Wqkt, bk, Kall, Pq);

    // scores (q fused) -> softmax -> hbar; W2 transpose rides along
    scores_plus_w2t<<<dim3(1024 + 8000), dim3(256), 0, stream>>>(
        x, Pq, bq, Kall, hbar, W2, W2t);

    // mid = relu(hbar @ Gt^T + b')
    gemm64<1, 1, 1><<<dim3(256 / 64, 4096 / 64), dim3(256), 0, stream>>>(
        hbar, Gtb, bprim, midb, 4096, 256, 768);

    // out = mid @ W2 + b2  (fp32)
    gemm_out<<<dim3(8000), dim3(256), 0, stream>>>(midb, W2t, b2, (float*)d_out);
}

// Round 10
// 307.678 us; speedup vs baseline: 2.3584x; 1.2066x over previous
//
#include <hip/hip_runtime.h>

#define Snum 2048
#define SCALE 0.08838834764831845f

typedef __attribute__((ext_vector_type(8))) __bf16 bf16x8;
typedef __attribute__((ext_vector_type(4))) float f32x4;

__device__ inline unsigned short f2bf(float f) {
    unsigned int u = __float_as_uint(f);
    unsigned int r = u + 0x7FFFu + ((u >> 16) & 1u);
    return (unsigned short)(r >> 16);
}
__device__ inline float bf2f(unsigned short u) {
    return __uint_as_float(((unsigned)u) << 16);
}
__device__ inline void gld_lds16(const unsigned short* g, unsigned short* l) {
    __builtin_amdgcn_global_load_lds(
        (const __attribute__((address_space(1))) unsigned int*)g,
        (__attribute__((address_space(3))) unsigned int*)l, 16, 0, 0);
}

// ---------------- weight prep: Wv cast, W1/Wk/Wq transposes ----------------
__global__ __launch_bounds__(256) void prep_weights(
    const float* __restrict__ Wv, unsigned short* __restrict__ Wvbf,   // [768][512] cast only
    const float* __restrict__ W1, unsigned short* __restrict__ W1t,    // [256][512]
    const float* __restrict__ Wk, const float* __restrict__ Wq,
    unsigned short* __restrict__ Wqkt)                                  // [256][768]
{
    const int id = blockIdx.x;
    if (id < 384) {
        const int base = (id * 256 + threadIdx.x) * 4;
        const float4 v = *(const float4*)(Wv + base);
        ushort4 o;
        o.x = f2bf(v.x); o.y = f2bf(v.y); o.z = f2bf(v.z); o.w = f2bf(v.w);
        *(ushort4*)(Wvbf + base) = o;
        return;
    }
    __shared__ float t[32][33];
    const float* in; unsigned short* out; int K, N, bx, by;
    if (id < 512)      { int q = id - 384; in = W1; out = W1t;  K = 512; N = 256; bx = q & 7; by = q >> 3; }
    else if (id < 608) { int q = id - 512; in = Wk; out = Wqkt; K = 768; N = 128; bx = q & 3; by = q >> 2; }
    else               { int q = id - 608; in = Wq; out = Wqkt + (size_t)128 * 768; K = 768; N = 128; bx = q & 3; by = q >> 2; }

    const int tx = threadIdx.x & 31, ty = threadIdx.x >> 5;
    #pragma unroll
    for (int i = 0; i < 4; ++i) {
        int k = by * 32 + ty + i * 8, n = bx * 32 + tx;
        t[ty + i * 8][tx] = in[(size_t)k * N + n];
    }
    __syncthreads();
    #pragma unroll
    for (int i = 0; i < 4; ++i) {
        int n = bx * 32 + ty + i * 8, k = by * 32 + tx;
        out[(size_t)n * K + k] = f2bf(t[tx][ty + i * 8]);
    }
}

// ---------------- Gt = W1t @ Wvbf^T  (48 blocks) + bias_prime (block 48) ----------------
__global__ __launch_bounds__(256) void gt_bias(
    const unsigned short* __restrict__ W1t,   // [256][512]
    const unsigned short* __restrict__ Wvbf,  // [768][512]
    const float* __restrict__ bv, const float* __restrict__ b1,
    unsigned short* __restrict__ Gtb,         // [256][768]
    float* __restrict__ bp)                   // [256]
{
    if (blockIdx.x == 48) {
        const int n = threadIdx.x;
        float s = b1[n];
        const unsigned short* row = W1t + (size_t)n * 512;
        for (int h = 0; h < 512; h += 8) {
            uint4 u = *(const uint4*)(row + h);
            const unsigned short* v = (const unsigned short*)&u;
            #pragma unroll
            for (int i = 0; i < 8; ++i) s += bv[h + i] * bf2f(v[i]);
        }
        bp[n] = s;
        return;
    }
    __shared__ __align__(16) unsigned short As[2][64 * 32];
    __shared__ __align__(16) unsigned short Bs[2][64 * 32];
    const int tid = threadIdx.x;
    const int bn = blockIdx.x % 12, bm = blockIdx.x / 12;
    const int wid = tid >> 6, lane = tid & 63;
    const int wm = (wid >> 1) * 32, wn = (wid & 1) * 32;
    const int lr = lane & 15, g = lane >> 4;
    const int r0 = bm * 64, c0 = bn * 64;
    const int K = 512, NT = 16, N = 768;
    const int srow = lane >> 2, skc = (lane & 3) * 8;

    f32x4 acc[2][2] = {};

    gld_lds16(W1t  + (size_t)(r0 + wid * 16 + srow) * K + skc, &As[0][wid * 16 * 32]);
    gld_lds16(Wvbf + (size_t)(c0 + wid * 16 + srow) * K + skc, &Bs[0][wid * 16 * 32]);
    __syncthreads();

    for (int t = 0; t < NT; ++t) {
        const int cur = t & 1, nxt = cur ^ 1;
        if (t + 1 < NT) {
            const int k0 = (t + 1) * 32;
            gld_lds16(W1t  + (size_t)(r0 + wid * 16 + srow) * K + k0 + skc, &As[nxt][wid * 16 * 32]);
            gld_lds16(Wvbf + (size_t)(c0 + wid * 16 + srow) * K + k0 + skc, &Bs[nxt][wid * 16 * 32]);
        }
        bf16x8 aF[2], bF[2];
        #pragma unroll
        for (int mm = 0; mm < 2; ++mm) aF[mm] = *(const bf16x8*)&As[cur][(wm + mm * 16 + lr) * 32 + g * 8];
        #pragma unroll
        for (int nn = 0; nn < 2; ++nn) bF[nn] = *(const bf16x8*)&Bs[cur][(wn + nn * 16 + lr) * 32 + g * 8];
        #pragma unroll
        for (int mm = 0; mm < 2; ++mm)
            #pragma unroll
            for (int nn = 0; nn < 2; ++nn)
                acc[mm][nn] = __builtin_amdgcn_mfma_f32_16x16x32_bf16(bF[nn], aF[mm], acc[mm][nn], 0, 0, 0);
        __syncthreads();
    }

    #pragma unroll
    for (int mm = 0; mm < 2; ++mm)
        #pragma unroll
        for (int nn = 0; nn < 2; ++nn) {
            const int orow = r0 + wm + mm * 16 + lr;
            const int colb = c0 + wn + nn * 16 + g * 4;
            unsigned short o[4];
            #pragma unroll
            for (int reg = 0; reg < 4; ++reg) o[reg] = f2bf(acc[mm][nn][reg]);
            *(ushort4*)&Gtb[(size_t)orow * N + colb] = *(ushort4*)o;
        }
}

// ---------------- proj_qk: one pass over x -> Kall = relu(x@Wk+bk), Pq = x@Wq ----------------
__global__ __launch_bounds__(256) void proj_qk(
    const float* __restrict__ x, const unsigned short* __restrict__ Bt,
    const float* __restrict__ bk,
    unsigned short* __restrict__ Kall,   // [49152][128] bf16
    unsigned short* __restrict__ Pq)     // [49152][128] bf16
{
    __shared__ __align__(16) unsigned short As[2][64 * 32];
    __shared__ __align__(16) unsigned short Bs[2][256 * 32];
    const int tid = threadIdx.x;
    const int wid = tid >> 6, lane = tid & 63;
    const int wn = wid * 64;
    const int lr = lane & 15, g = lane >> 4;
    const int r0 = blockIdx.x * 64;
    const int K = 768, NT = 24;

    const int arow = tid >> 2, akc = (tid & 3) * 8;

    f32x4 acc[4][4] = {};

    float4 a0 = *(const float4*)(x + (size_t)(r0 + arow) * K + akc);
    float4 a1 = *(const float4*)(x + (size_t)(r0 + arow) * K + akc + 4);
    {
        unsigned short v[8];
        v[0] = f2bf(a0.x); v[1] = f2bf(a0.y); v[2] = f2bf(a0.z); v[3] = f2bf(a0.w);
        v[4] = f2bf(a1.x); v[5] = f2bf(a1.y); v[6] = f2bf(a1.z); v[7] = f2bf(a1.w);
        *(uint4*)&As[0][arow * 32 + akc] = *(uint4*)v;
    }
    #pragma unroll
    for (int c = 0; c < 4; ++c) {
        const int rr = wid * 64 + c * 16;
        gld_lds16(Bt + (size_t)(rr + (lane >> 2)) * K + (lane & 3) * 8, &Bs[0][rr * 32]);
    }
    __syncthreads();

    for (int t = 0; t < NT; ++t) {
        const int cur = t & 1, nxt = cur ^ 1;
        if (t + 1 < NT) {
            const int k0 = (t + 1) * 32;
            a0 = *(const float4*)(x + (size_t)(r0 + arow) * K + k0 + akc);
            a1 = *(const float4*)(x + (size_t)(r0 + arow) * K + k0 + akc + 4);
            #pragma unroll
            for (int c = 0; c < 4; ++c) {
                const int rr = wid * 64 + c * 16;
                gld_lds16(Bt + (size_t)(rr + (lane >> 2)) * K + k0 + (lane & 3) * 8,
                          &Bs[nxt][rr * 32]);
            }
        }

        bf16x8 aF[4], bF[4];
        #pragma unroll
        for (int mm = 0; mm < 4; ++mm) aF[mm] = *(const bf16x8*)&As[cur][(mm * 16 + lr) * 32 + g * 8];
        #pragma unroll
        for (int nn = 0; nn < 4; ++nn) bF[nn] = *(const bf16x8*)&Bs[cur][(wn + nn * 16 + lr) * 32 + g * 8];
        #pragma unroll
        for (int mm = 0; mm < 4; ++mm)
            #pragma unroll
            for (int nn = 0; nn < 4; ++nn)
                acc[mm][nn] = __builtin_amdgcn_mfma_f32_16x16x32_bf16(bF[nn], aF[mm], acc[mm][nn], 0, 0, 0);

        if (t + 1 < NT) {
            unsigned short v[8];
            v[0] = f2bf(a0.x); v[1] = f2bf(a0.y); v[2] = f2bf(a0.z); v[3] = f2bf(a0.w);
            v[4] = f2bf(a1.x); v[5] = f2bf(a1.y); v[6] = f2bf(a1.z); v[7] = f2bf(a1.w);
            *(uint4*)&As[nxt][arow * 32 + akc] = *(uint4*)v;
        }
        __syncthreads();
    }

    #pragma unroll
    for (int mm = 0; mm < 4; ++mm)
        #pragma unroll
        for (int nn = 0; nn < 4; ++nn) {
            const int row = r0 + mm * 16 + lr;
            const int colb = wn + nn * 16 + g * 4;
            unsigned short o[4];
            if (colb < 128) {
                #pragma unroll
                for (int reg = 0; reg < 4; ++reg) {
                    float kv = acc[mm][nn][reg] + bk[colb + reg];
                    o[reg] = f2bf(kv > 0.f ? kv : 0.f);
                }
                *(ushort4*)&Kall[(size_t)row * 128 + colb] = *(ushort4*)o;
            } else {
                #pragma unroll
                for (int reg = 0; reg < 4; ++reg) o[reg] = f2bf(acc[mm][nn][reg]);
                *(ushort4*)&Pq[(size_t)row * 128 + (colb - 128)] = *(ushort4*)o;
            }
        }
}

// ---------------- scores + softmax + hbar, with W2 transpose blocks riding along ----------------
__global__ __launch_bounds__(256) void scores_plus_w2t(
    const float* __restrict__ x,
    const unsigned short* __restrict__ Pq,
    const float* __restrict__ bq,
    const unsigned short* __restrict__ Kall,
    unsigned short* __restrict__ hbar,
    const float* __restrict__ W2, unsigned short* __restrict__ W2t)
{
    if (blockIdx.x >= 1024) {
        __shared__ float t[32][33];
        const int id = blockIdx.x - 1024;
        const int bx = id >> 3, by = id & 7;
        const int tx = threadIdx.x & 31, ty = threadIdx.x >> 5;
        #pragma unroll
        for (int i = 0; i < 4; ++i) {
            int k = by * 32 + ty + i * 8, n = bx * 32 + tx;
            t[ty + i * 8][tx] = W2[(size_t)k * 32000 + n];
        }
        __syncthreads();
        #pragma unroll
        for (int i = 0; i < 4; ++i) {
            int n = bx * 32 + ty + i * 8, k = by * 32 + tx;
            W2t[(size_t)n * 256 + k] = f2bf(t[tx][ty + i * 8]);
        }
        return;
    }

    const int wid = threadIdx.x >> 6, lane = threadIdx.x & 63;
    const int r = blockIdx.x * 4 + wid;
    const int b = r >> 11, s = r & 2047;

    float qa = 0.f, qb_ = 0.f;
    #pragma unroll
    for (int l = 0; l < 12; ++l) {
        const unsigned short* prow = Pq + ((size_t)(l * 2 + b) * Snum + s) * 128 + lane * 2;
        unsigned int u = *(const unsigned int*)prow;
        qa += bf2f((unsigned short)(u & 0xFFFF));
        qb_ += bf2f((unsigned short)(u >> 16));
    }
    float q0 = qa * (1.0f / 12.0f) + bq[lane * 2];
    float q1 = qb_ * (1.0f / 12.0f) + bq[lane * 2 + 1];
    q0 = q0 > 0.f ? q0 : 0.f;
    q1 = q1 > 0.f ? q1 : 0.f;
    q0 = bf2f(f2bf(q0)); q1 = bf2f(f2bf(q1));

    float sc[12];
    #pragma unroll
    for (int l = 0; l < 12; ++l) {
        const unsigned short* krow = Kall + ((size_t)(l * 2 + b) * Snum + s) * 128 + lane * 2;
        unsigned int u = *(const unsigned int*)krow;
        float p = q0 * bf2f((unsigned short)(u & 0xFFFF)) + q1 * bf2f((unsigned short)(u >> 16));
        #pragma unroll
        for (int off = 32; off > 0; off >>= 1) p += __shfl_xor(p, off, 64);
        sc[l] = p * SCALE;
    }
    float m = sc[0];
    #pragma unroll
    for (int l = 1; l < 12; ++l) m = fmaxf(m, sc[l]);
    float att[12], den = 0.f;
    #pragma unroll
    for (int l = 0; l < 12; ++l) { att[l] = __expf(sc[l] - m); den += att[l]; }
    const float inv = 1.0f / den;
    #pragma unroll
    for (int l = 0; l < 12; ++l) att[l] *= inv;

    #pragma unroll
    for (int jv = 0; jv < 3; ++jv) {
        const int d0 = jv * 256 + lane * 4;
        float a0 = 0.f, a1 = 0.f, a2 = 0.f, a3 = 0.f;
        #pragma unroll
        for (int l = 0; l < 12; ++l) {
            const float4 v = *(const float4*)(x + ((size_t)(l * 2 + b) * Snum + s) * 768 + d0);
            a0 += att[l] * v.x; a1 += att[l] * v.y; a2 += att[l] * v.z; a3 += att[l] * v.w;
        }
        ushort4 o;
        o.x = f2bf(a0); o.y = f2bf(a1); o.z = f2bf(a2); o.w = f2bf(a3);
        *(ushort4*)(hbar + (size_t)r * 768 + d0) = o;
    }
}

// ---------------- 64x64 bf16 MFMA GEMM, dbuf gld_lds staging, swapped epilogue ----------------
template <int RELU, int OUT_BF16, int BIAS>
__global__ __launch_bounds__(256) void gemm64(
    const unsigned short* __restrict__ A, const unsigned short* __restrict__ Bt,
    const float* __restrict__ bias, void* __restrict__ out, int M, int N, int K)
{
    __shared__ __align__(16) unsigned short As[2][64 * 32];
    __shared__ __align__(16) unsigned short Bs[2][64 * 32];
    const int tid = threadIdx.x;
    const int bn = blockIdx.x, bm = blockIdx.y;
    const int wid = tid >> 6, lane = tid & 63;
    const int wm = (wid >> 1) * 32, wn = (wid & 1) * 32;
    const int lr = lane & 15, g = lane >> 4;
    const int r0 = bm * 64, c0 = bn * 64;
    const int NT = K / 32;

    const int srow = lane >> 2, skc = (lane & 3) * 8;

    f32x4 acc[2][2] = {};

    gld_lds16(A  + (size_t)(r0 + wid * 16 + srow) * K + skc, &As[0][wid * 16 * 32]);
    gld_lds16(Bt + (size_t)(c0 + wid * 16 + srow) * K + skc, &Bs[0][wid * 16 * 32]);
    __syncthreads();

    for (int t = 0; t < NT; ++t) {
        const int cur = t & 1, nxt = cur ^ 1;
        if (t + 1 < NT) {
            const int k0 = (t + 1) * 32;
            gld_lds16(A  + (size_t)(r0 + wid * 16 + srow) * K + k0 + skc, &As[nxt][wid * 16 * 32]);
            gld_lds16(Bt + (size_t)(c0 + wid * 16 + srow) * K + k0 + skc, &Bs[nxt][wid * 16 * 32]);
        }

        bf16x8 aF[2], bF[2];
        #pragma unroll
        for (int mm = 0; mm < 2; ++mm) aF[mm] = *(const bf16x8*)&As[cur][(wm + mm * 16 + lr) * 32 + g * 8];
        #pragma unroll
        for (int nn = 0; nn < 2; ++nn) bF[nn] = *(const bf16x8*)&Bs[cur][(wn + nn * 16 + lr) * 32 + g * 8];
        #pragma unroll
        for (int mm = 0; mm < 2; ++mm)
            #pragma unroll
            for (int nn = 0; nn < 2; ++nn)
                acc[mm][nn] = __builtin_amdgcn_mfma_f32_16x16x32_bf16(bF[nn], aF[mm], acc[mm][nn], 0, 0, 0);
        __syncthreads();
    }

    #pragma unroll
    for (int mm = 0; mm < 2; ++mm)
        #pragma unroll
        for (int nn = 0; nn < 2; ++nn) {
            const int orow = r0 + wm + mm * 16 + lr;
            const int colb = c0 + wn + nn * 16 + g * 4;
            float vr[4];
            #pragma unroll
            for (int reg = 0; reg < 4; ++reg) {
                float v = acc[mm][nn][reg] + (BIAS ? bias[colb + reg] : 0.f);
                vr[reg] = (RELU && v < 0.f) ? 0.f : v;
            }
            if (OUT_BF16) {
                unsigned short o[4];
                #pragma unroll
                for (int reg = 0; reg < 4; ++reg) o[reg] = f2bf(vr[reg]);
                *(ushort4*)&((unsigned short*)out)[(size_t)orow * N + colb] = *(ushort4*)o;
            } else {
                *(float4*)&((float*)out)[(size_t)orow * N + colb] = *(float4*)vr;
            }
        }
}

// ---------------- final GEMM: B-stationary, one barrier, XOR-swizzled LDS, A from L2 ----------------
// out = mid @ W2t^T + b2. M=4096, N=32000, K=256.
// Grid 2000: bn in [0,500) 64-col panels (B panel 32KB in LDS once), mg in [0,4) row groups;
// each block sweeps 4 m-steps of 256 rows (wave = 64 rows x 64 cols, acc 4x4).
__global__ __launch_bounds__(256) void gemm_out(
    const unsigned short* __restrict__ A,   // [4096][256] bf16
    const unsigned short* __restrict__ Bt,  // [32000][256] bf16
    const float* __restrict__ bias, float* __restrict__ out)
{
    __shared__ __align__(16) unsigned short Bs[64 * 256];  // 32 KB, 16B-slot XOR swizzle
    const int K = 256, N = 32000;
    const int orig = blockIdx.x;                  // 2000
    const int swz = (orig & 7) * 250 + (orig >> 3);
    const int bn = swz >> 2;                      // [0,500) — per-XCD bn span ~63 -> 2MB B panel
    const int mg = swz & 3;                       // [0,4)
    const int tid = threadIdx.x;
    const int wid = tid >> 6, lane = tid & 63;
    const int lr = lane & 15, g = lane >> 4;
    const int c0 = bn * 64;

    // stage B panel once: slot (col, s) holds global k-slot s  (source pre-swizzled: s^(col&7))
    #pragma unroll
    for (int c = 0; c < 8; ++c) {
        const int i = wid * 8 + c;                // 32 instrs: 2 cols each
        const int col = i * 2 + (lane >> 5);
        const int slot = lane & 31;               // 16B k-slot within col
        gld_lds16(Bt + (size_t)(c0 + col) * K + (size_t)((slot ^ (col & 7)) * 8),
                  &Bs[i * 512]);
    }
    __syncthreads();

    for (int ms = 0; ms < 4; ++ms) {
        const int r0 = mg * 1024 + ms * 256 + wid * 64;
        f32x4 acc[4][4] = {};
        #pragma unroll
        for (int kf = 0; kf < 8; ++kf) {
            bf16x8 aF[4], bF[4];
            #pragma unroll
            for (int rf = 0; rf < 4; ++rf)
                aF[rf] = *(const bf16x8*)(A + (size_t)(r0 + rf * 16 + lr) * K + kf * 32 + g * 8);
            #pragma unroll
            for (int cf = 0; cf < 4; ++cf) {
                const int col = cf * 16 + lr;
                const int slot = (kf * 4 + g) ^ (lr & 7);   // read-side XOR (col&7 == lr&7)
                bF[cf] = *(const bf16x8*)&Bs[(col * 32 + slot) * 8];
            }
            #pragma unroll
            for (int rf = 0; rf < 4; ++rf)
                #pragma unroll
                for (int cf = 0; cf < 4; ++cf)
                    acc[rf][cf] = __builtin_amdgcn_mfma_f32_16x16x32_bf16(bF[cf], aF[rf], acc[rf][cf], 0, 0, 0);
        }

        // swapped epilogue: lane owns row = lr, 4 consecutive cols (full 64B sector per instr)
        #pragma unroll
        for (int rf = 0; rf < 4; ++rf)
            #pragma unroll
            for (int cf = 0; cf < 4; ++cf) {
                const int row = r0 + rf * 16 + lr;
                const int colb = c0 + cf * 16 + g * 4;
                const float4 b4 = *(const float4*)&bias[colb];
                f32x4 o = acc[rf][cf];
                o[0] += b4.x; o[1] += b4.y; o[2] += b4.z; o[3] += b4.w;
                __builtin_nontemporal_store(o, (f32x4*)&out[(size_t)row * N + colb]);
            }
    }
}

extern "C" void kernel_launch(void* const* d_in, const int* in_sizes, int n_in,
                              void* d_out, int out_size, void* d_ws, size_t ws_size,
                              hipStream_t stream) {
    (void)in_sizes; (void)n_in; (void)out_size; (void)ws_size;

    const float* x  = (const float*)d_in[0];
    const float* Wq = (const float*)d_in[1];
    const float* bq = (const float*)d_in[2];
    const float* Wk = (const float*)d_in[3];
    const float* bk = (const float*)d_in[4];
    const float* Wv = (const float*)d_in[5];
    const float* bv = (const float*)d_in[6];
    const float* W1 = (const float*)d_in[7];
    const float* b1 = (const float*)d_in[8];
    const float* W2 = (const float*)d_in[9];
    const float* b2 = (const float*)d_in[10];

    char* p = (char*)d_ws;
    unsigned short* Wqkt  = (unsigned short*)p; p += (size_t)256 * 768 * 2;
    unsigned short* Wvbf  = (unsigned short*)p; p += (size_t)768 * 512 * 2;
    unsigned short* W1t   = (unsigned short*)p; p += (size_t)256 * 512 * 2;
    unsigned short* Gtb   = (unsigned short*)p; p += (size_t)256 * 768 * 2;
    float*          bprim = (float*)p;          p += (size_t)256 * 4;
    unsigned short* W2t   = (unsigned short*)p; p += (size_t)32000 * 256 * 2;
    unsigned short* Kall  = (unsigned short*)p; p += (size_t)49152 * 128 * 2;
    unsigned short* Pq    = (unsigned short*)p; p += (size_t)49152 * 128 * 2;
    unsigned short* hbar  = (unsigned short*)p; p += (size_t)4096 * 768 * 2;
    unsigned short* midb  = (unsigned short*)p; p += (size_t)4096 * 256 * 2;

    // weight prep: Wv cast, W1t, Wqkt
    prep_weights<<<dim3(704), dim3(256), 0, stream>>>(Wv, Wvbf, W1, W1t, Wk, Wq, Wqkt);

    // Gt = (Wv@W1)^T and b' = bv@W1 + b1, one launch
    gt_bias<<<dim3(49), dim3(256), 0, stream>>>(W1t, Wvbf, bv, b1, Gtb, bprim);

    // one pass over x: Kall = relu(x@Wk+bk), Pq = x@Wq
    proj_qk<<<dim3(49152 / 64), dim3(256), 0, stream>>>(x, Wqkt, bk, Kall, Pq);

    // scores (q fused) -> softmax -> hbar; W2 transpose rides along
    scores_plus_w2t<<<dim3(1024 + 8000), dim3(256), 0, stream>>>(
        x, Pq, bq, Kall, hbar, W2, W2t);

    // mid = relu(hbar @ Gt^T + b')
    gemm64<1, 1, 1><<<dim3(256 / 64, 4096 / 64), dim3(256), 0, stream>>>(
        hbar, Gtb, bprim, midb, 4096, 256, 768);

    // out = mid @ W2 + b2  (fp32)
    gemm_out<<<dim3(2000), dim3(256), 0, stream>>>(midb, W2t, b2, (float*)d_out);
}

// Round 12
// 284.242 us; speedup vs baseline: 2.5529x; 1.0825x over previous
//
#include <hip/hip_runtime.h>

#define Snum 2048
#define SCALE 0.08838834764831845f

typedef __attribute__((ext_vector_type(8))) __bf16 bf16x8;
typedef __attribute__((ext_vector_type(4))) float f32x4;

__device__ inline unsigned short f2bf(float f) {
    unsigned int u = __float_as_uint(f);
    unsigned int r = u + 0x7FFFu + ((u >> 16) & 1u);
    return (unsigned short)(r >> 16);
}
__device__ inline float bf2f(unsigned short u) {
    return __uint_as_float(((unsigned)u) << 16);
}
__device__ inline void gld_lds16(const unsigned short* g, unsigned short* l) {
    __builtin_amdgcn_global_load_lds(
        (const __attribute__((address_space(1))) unsigned int*)g,
        (__attribute__((address_space(3))) unsigned int*)l, 16, 0, 0);
}

// ---------------- ONE prep launch: Wqkt transposes + Gt=Wv@W1 (fp32) + b'=bv@W1+b1 ----------------
// blocks 0-95: Wk^T; 96-191: Wq^T; 192-287: Gt (8 v-rows each); 288: bias.
__global__ __launch_bounds__(256) void prep_all(
    const float* __restrict__ Wk, const float* __restrict__ Wq,
    unsigned short* __restrict__ Wqkt,        // [256][768]
    const float* __restrict__ Wv,             // [768][512]
    const float* __restrict__ W1,             // [512][256]
    const float* __restrict__ bv, const float* __restrict__ b1,
    unsigned short* __restrict__ Gtb,         // [256][768]  (G=Wv@W1, stored transposed)
    float* __restrict__ bp)                   // [256]
{
    const int id = blockIdx.x;
    const int tid = threadIdx.x;

    if (id < 192) {
        // 32x32 tiled transpose fp32->bf16: [768][128] -> [128][768]
        __shared__ float t[32][33];
        const int q = (id < 96) ? id : (id - 96);   // FIX: 95 is not a pow2-1 mask
        const float* in = (id < 96) ? Wk : Wq;
        unsigned short* out = Wqkt + (id < 96 ? 0 : (size_t)128 * 768);
        const int bx = q & 3, by = q >> 2;     // N/32=4, K/32=24
        const int tx = tid & 31, ty = tid >> 5;
        #pragma unroll
        for (int i = 0; i < 4; ++i) {
            int k = by * 32 + ty + i * 8, n = bx * 32 + tx;
            t[ty + i * 8][tx] = in[(size_t)k * 128 + n];
        }
        __syncthreads();
        #pragma unroll
        for (int i = 0; i < 4; ++i) {
            int n = bx * 32 + ty + i * 8, k = by * 32 + tx;
            out[(size_t)n * 768 + k] = f2bf(t[tx][ty + i * 8]);
        }
        return;
    }

    if (id == 288) {
        // b'[n] = b1[n] + sum_h bv[h] * W1[h][n]
        const int n = tid;
        float s = b1[n];
        for (int h = 0; h < 512; ++h) s += bv[h] * W1[(size_t)h * 256 + n];
        bp[n] = s;
        return;
    }

    // Gt blocks: 8 rows of Wv staged in LDS; thread n accumulates 8 outputs in fp32.
    __shared__ float wv[8][512];               // 16 KB
    const int v0 = (id - 192) * 8;
    for (int i = tid; i < 8 * 512; i += 256) {
        const int v = i >> 9, h = i & 511;
        wv[v][h] = Wv[(size_t)(v0 + v) * 512 + h];
    }
    __syncthreads();

    const int n = tid;
    float acc[8] = {};
    for (int h = 0; h < 512; ++h) {
        const float w1 = W1[(size_t)h * 256 + n];
        #pragma unroll
        for (int v = 0; v < 8; ++v) acc[v] += wv[v][h] * w1;
    }
    unsigned short o[8];
    #pragma unroll
    for (int v = 0; v < 8; ++v) o[v] = f2bf(acc[v]);
    *(ushort4*)&Gtb[(size_t)n * 768 + v0]     = *(ushort4*)&o[0];
    *(ushort4*)&Gtb[(size_t)n * 768 + v0 + 4] = *(ushort4*)&o[4];
}

// ---------------- proj_qk: one pass over x -> Kall = relu(x@Wk+bk), Pq = x@Wq ----------------
__global__ __launch_bounds__(256) void proj_qk(
    const float* __restrict__ x, const unsigned short* __restrict__ Bt,
    const float* __restrict__ bk,
    unsigned short* __restrict__ Kall,   // [49152][128] bf16
    unsigned short* __restrict__ Pq)     // [49152][128] bf16
{
    __shared__ __align__(16) unsigned short As[2][64 * 32];
    __shared__ __align__(16) unsigned short Bs[2][256 * 32];
    const int tid = threadIdx.x;
    const int wid = tid >> 6, lane = tid & 63;
    const int wn = wid * 64;
    const int lr = lane & 15, g = lane >> 4;
    const int r0 = blockIdx.x * 64;
    const int K = 768, NT = 24;

    const int arow = tid >> 2, akc = (tid & 3) * 8;

    f32x4 acc[4][4] = {};

    float4 a0 = *(const float4*)(x + (size_t)(r0 + arow) * K + akc);
    float4 a1 = *(const float4*)(x + (size_t)(r0 + arow) * K + akc + 4);
    {
        unsigned short v[8];
        v[0] = f2bf(a0.x); v[1] = f2bf(a0.y); v[2] = f2bf(a0.z); v[3] = f2bf(a0.w);
        v[4] = f2bf(a1.x); v[5] = f2bf(a1.y); v[6] = f2bf(a1.z); v[7] = f2bf(a1.w);
        *(uint4*)&As[0][arow * 32 + akc] = *(uint4*)v;
    }
    #pragma unroll
    for (int c = 0; c < 4; ++c) {
        const int rr = wid * 64 + c * 16;
        gld_lds16(Bt + (size_t)(rr + (lane >> 2)) * K + (lane & 3) * 8, &Bs[0][rr * 32]);
    }
    __syncthreads();

    for (int t = 0; t < NT; ++t) {
        const int cur = t & 1, nxt = cur ^ 1;
        if (t + 1 < NT) {
            const int k0 = (t + 1) * 32;
            a0 = *(const float4*)(x + (size_t)(r0 + arow) * K + k0 + akc);
            a1 = *(const float4*)(x + (size_t)(r0 + arow) * K + k0 + akc + 4);
            #pragma unroll
            for (int c = 0; c < 4; ++c) {
                const int rr = wid * 64 + c * 16;
                gld_lds16(Bt + (size_t)(rr + (lane >> 2)) * K + k0 + (lane & 3) * 8,
                          &Bs[nxt][rr * 32]);
            }
        }

        bf16x8 aF[4], bF[4];
        #pragma unroll
        for (int mm = 0; mm < 4; ++mm) aF[mm] = *(const bf16x8*)&As[cur][(mm * 16 + lr) * 32 + g * 8];
        #pragma unroll
        for (int nn = 0; nn < 4; ++nn) bF[nn] = *(const bf16x8*)&Bs[cur][(wn + nn * 16 + lr) * 32 + g * 8];
        #pragma unroll
        for (int mm = 0; mm < 4; ++mm)
            #pragma unroll
            for (int nn = 0; nn < 4; ++nn)
                acc[mm][nn] = __builtin_amdgcn_mfma_f32_16x16x32_bf16(bF[nn], aF[mm], acc[mm][nn], 0, 0, 0);

        if (t + 1 < NT) {
            unsigned short v[8];
            v[0] = f2bf(a0.x); v[1] = f2bf(a0.y); v[2] = f2bf(a0.z); v[3] = f2bf(a0.w);
            v[4] = f2bf(a1.x); v[5] = f2bf(a1.y); v[6] = f2bf(a1.z); v[7] = f2bf(a1.w);
            *(uint4*)&As[nxt][arow * 32 + akc] = *(uint4*)v;
        }
        __syncthreads();
    }

    #pragma unroll
    for (int mm = 0; mm < 4; ++mm)
        #pragma unroll
        for (int nn = 0; nn < 4; ++nn) {
            const int row = r0 + mm * 16 + lr;
            const int colb = wn + nn * 16 + g * 4;
            unsigned short o[4];
            if (colb < 128) {
                #pragma unroll
                for (int reg = 0; reg < 4; ++reg) {
                    float kv = acc[mm][nn][reg] + bk[colb + reg];
                    o[reg] = f2bf(kv > 0.f ? kv : 0.f);
                }
                *(ushort4*)&Kall[(size_t)row * 128 + colb] = *(ushort4*)o;
            } else {
                #pragma unroll
                for (int reg = 0; reg < 4; ++reg) o[reg] = f2bf(acc[mm][nn][reg]);
                *(ushort4*)&Pq[(size_t)row * 128 + (colb - 128)] = *(ushort4*)o;
            }
        }
}

// ---------------- scores + softmax + hbar, with W2 transpose blocks riding along ----------------
__global__ __launch_bounds__(256) void scores_plus_w2t(
    const float* __restrict__ x,
    const unsigned short* __restrict__ Pq,
    const float* __restrict__ bq,
    const unsigned short* __restrict__ Kall,
    unsigned short* __restrict__ hbar,
    const float* __restrict__ W2, unsigned short* __restrict__ W2t)
{
    if (blockIdx.x >= 1024) {
        __shared__ float t[32][33];
        const int id = blockIdx.x - 1024;
        const int bx = id >> 3, by = id & 7;
        const int tx = threadIdx.x & 31, ty = threadIdx.x >> 5;
        #pragma unroll
        for (int i = 0; i < 4; ++i) {
            int k = by * 32 + ty + i * 8, n = bx * 32 + tx;
            t[ty + i * 8][tx] = W2[(size_t)k * 32000 + n];
        }
        __syncthreads();
        #pragma unroll
        for (int i = 0; i < 4; ++i) {
            int n = bx * 32 + ty + i * 8, k = by * 32 + tx;
            W2t[(size_t)n * 256 + k] = f2bf(t[tx][ty + i * 8]);
        }
        return;
    }

    const int wid = threadIdx.x >> 6, lane = threadIdx.x & 63;
    const int r = blockIdx.x * 4 + wid;
    const int b = r >> 11, s = r & 2047;

    float qa = 0.f, qb_ = 0.f;
    #pragma unroll
    for (int l = 0; l < 12; ++l) {
        const unsigned short* prow = Pq + ((size_t)(l * 2 + b) * Snum + s) * 128 + lane * 2;
        unsigned int u = *(const unsigned int*)prow;
        qa += bf2f((unsigned short)(u & 0xFFFF));
        qb_ += bf2f((unsigned short)(u >> 16));
    }
    float q0 = qa * (1.0f / 12.0f) + bq[lane * 2];
    float q1 = qb_ * (1.0f / 12.0f) + bq[lane * 2 + 1];
    q0 = q0 > 0.f ? q0 : 0.f;
    q1 = q1 > 0.f ? q1 : 0.f;
    q0 = bf2f(f2bf(q0)); q1 = bf2f(f2bf(q1));

    float sc[12];
    #pragma unroll
    for (int l = 0; l < 12; ++l) {
        const unsigned short* krow = Kall + ((size_t)(l * 2 + b) * Snum + s) * 128 + lane * 2;
        unsigned int u = *(const unsigned int*)krow;
        float p = q0 * bf2f((unsigned short)(u & 0xFFFF)) + q1 * bf2f((unsigned short)(u >> 16));
        #pragma unroll
        for (int off = 32; off > 0; off >>= 1) p += __shfl_xor(p, off, 64);
        sc[l] = p * SCALE;
    }
    float m = sc[0];
    #pragma unroll
    for (int l = 1; l < 12; ++l) m = fmaxf(m, sc[l]);
    float att[12], den = 0.f;
    #pragma unroll
    for (int l = 0; l < 12; ++l) { att[l] = __expf(sc[l] - m); den += att[l]; }
    const float inv = 1.0f / den;
    #pragma unroll
    for (int l = 0; l < 12; ++l) att[l] *= inv;

    #pragma unroll
    for (int jv = 0; jv < 3; ++jv) {
        const int d0 = jv * 256 + lane * 4;
        float a0 = 0.f, a1 = 0.f, a2 = 0.f, a3 = 0.f;
        #pragma unroll
        for (int l = 0; l < 12; ++l) {
            const float4 v = *(const float4*)(x + ((size_t)(l * 2 + b) * Snum + s) * 768 + d0);
            a0 += att[l] * v.x; a1 += att[l] * v.y; a2 += att[l] * v.z; a3 += att[l] * v.w;
        }
        ushort4 o;
        o.x = f2bf(a0); o.y = f2bf(a1); o.z = f2bf(a2); o.w = f2bf(a3);
        *(ushort4*)(hbar + (size_t)r * 768 + d0) = o;
    }
}

// ---------------- 64x64 bf16 MFMA GEMM, dbuf gld_lds staging, swapped epilogue ----------------
template <int RELU, int OUT_BF16, int BIAS>
__global__ __launch_bounds__(256) void gemm64(
    const unsigned short* __restrict__ A, const unsigned short* __restrict__ Bt,
    const float* __restrict__ bias, void* __restrict__ out, int M, int N, int K)
{
    __shared__ __align__(16) unsigned short As[2][64 * 32];
    __shared__ __align__(16) unsigned short Bs[2][64 * 32];
    const int tid = threadIdx.x;
    const int bn = blockIdx.x, bm = blockIdx.y;
    const int wid = tid >> 6, lane = tid & 63;
    const int wm = (wid >> 1) * 32, wn = (wid & 1) * 32;
    const int lr = lane & 15, g = lane >> 4;
    const int r0 = bm * 64, c0 = bn * 64;
    const int NT = K / 32;

    const int srow = lane >> 2, skc = (lane & 3) * 8;

    f32x4 acc[2][2] = {};

    gld_lds16(A  + (size_t)(r0 + wid * 16 + srow) * K + skc, &As[0][wid * 16 * 32]);
    gld_lds16(Bt + (size_t)(c0 + wid * 16 + srow) * K + skc, &Bs[0][wid * 16 * 32]);
    __syncthreads();

    for (int t = 0; t < NT; ++t) {
        const int cur = t & 1, nxt = cur ^ 1;
        if (t + 1 < NT) {
            const int k0 = (t + 1) * 32;
            gld_lds16(A  + (size_t)(r0 + wid * 16 + srow) * K + k0 + skc, &As[nxt][wid * 16 * 32]);
            gld_lds16(Bt + (size_t)(c0 + wid * 16 + srow) * K + k0 + skc, &Bs[nxt][wid * 16 * 32]);
        }

        bf16x8 aF[2], bF[2];
        #pragma unroll
        for (int mm = 0; mm < 2; ++mm) aF[mm] = *(const bf16x8*)&As[cur][(wm + mm * 16 + lr) * 32 + g * 8];
        #pragma unroll
        for (int nn = 0; nn < 2; ++nn) bF[nn] = *(const bf16x8*)&Bs[cur][(wn + nn * 16 + lr) * 32 + g * 8];
        #pragma unroll
        for (int mm = 0; mm < 2; ++mm)
            #pragma unroll
            for (int nn = 0; nn < 2; ++nn)
                acc[mm][nn] = __builtin_amdgcn_mfma_f32_16x16x32_bf16(bF[nn], aF[mm], acc[mm][nn], 0, 0, 0);
        __syncthreads();
    }

    #pragma unroll
    for (int mm = 0; mm < 2; ++mm)
        #pragma unroll
        for (int nn = 0; nn < 2; ++nn) {
            const int orow = r0 + wm + mm * 16 + lr;
            const int colb = c0 + wn + nn * 16 + g * 4;
            float vr[4];
            #pragma unroll
            for (int reg = 0; reg < 4; ++reg) {
                float v = acc[mm][nn][reg] + (BIAS ? bias[colb + reg] : 0.f);
                vr[reg] = (RELU && v < 0.f) ? 0.f : v;
            }
            if (OUT_BF16) {
                unsigned short o[4];
                #pragma unroll
                for (int reg = 0; reg < 4; ++reg) o[reg] = f2bf(vr[reg]);
                *(ushort4*)&((unsigned short*)out)[(size_t)orow * N + colb] = *(ushort4*)o;
            } else {
                *(float4*)&((float*)out)[(size_t)orow * N + colb] = *(float4*)vr;
            }
        }
}

// ---------------- final GEMM (R7-exact): BK=32/32KB dbuf, 16x16 frags, nt stores ----------------
__global__ __launch_bounds__(256) void gemm_out(
    const unsigned short* __restrict__ A,   // [4096][256] bf16
    const unsigned short* __restrict__ Bt,  // [32000][256] bf16
    const float* __restrict__ bias, float* __restrict__ out)
{
    __shared__ __align__(16) unsigned short As[2][128 * 32];  // 2 x 8 KB
    __shared__ __align__(16) unsigned short Bs[2][128 * 32];
    const int K = 256, N = 32000, NT = 8;
    const int orig = blockIdx.x;
    const int swz = (orig & 7) * 1000 + (orig >> 3);
    const int bn = swz >> 5, bm = swz & 31;
    const int tid = threadIdx.x;
    const int wid = tid >> 6, lane = tid & 63;
    const int wm = (wid >> 1) * 64, wn = (wid & 1) * 64;
    const int lr = lane & 15, g = lane >> 4;
    const int r0 = bm * 128, c0 = bn * 128;

    f32x4 acc[4][4] = {};

    #pragma unroll
    for (int c = 0; c < 2; ++c) {
        const int rr = wid * 32 + c * 16;
        gld_lds16(A  + (size_t)(r0 + rr + (lane >> 2)) * K + (lane & 3) * 8, &As[0][rr * 32]);
        gld_lds16(Bt + (size_t)(c0 + rr + (lane >> 2)) * K + (lane & 3) * 8, &Bs[0][rr * 32]);
    }
    __syncthreads();

    for (int t = 0; t < NT; ++t) {
        const int cur = t & 1, nxt = cur ^ 1;
        if (t + 1 < NT) {
            const int k0 = (t + 1) * 32;
            #pragma unroll
            for (int c = 0; c < 2; ++c) {
                const int rr = wid * 32 + c * 16;
                gld_lds16(A  + (size_t)(r0 + rr + (lane >> 2)) * K + k0 + (lane & 3) * 8, &As[nxt][rr * 32]);
                gld_lds16(Bt + (size_t)(c0 + rr + (lane >> 2)) * K + k0 + (lane & 3) * 8, &Bs[nxt][rr * 32]);
            }
        }

        bf16x8 aF[4], bF[4];
        #pragma unroll
        for (int mm = 0; mm < 4; ++mm) aF[mm] = *(const bf16x8*)&As[cur][(wm + mm * 16 + lr) * 32 + g * 8];
        #pragma unroll
        for (int nn = 0; nn < 4; ++nn) bF[nn] = *(const bf16x8*)&Bs[cur][(wn + nn * 16 + lr) * 32 + g * 8];
        #pragma unroll
        for (int mm = 0; mm < 4; ++mm)
            #pragma unroll
            for (int nn = 0; nn < 4; ++nn)
                acc[mm][nn] = __builtin_amdgcn_mfma_f32_16x16x32_bf16(bF[nn], aF[mm], acc[mm][nn], 0, 0, 0);
        __syncthreads();
    }

    #pragma unroll
    for (int mm = 0; mm < 4; ++mm)
        #pragma unroll
        for (int nn = 0; nn < 4; ++nn) {
            const int row = r0 + wm + mm * 16 + lr;
            const int colb = c0 + wn + nn * 16 + g * 4;
            const float4 b4 = *(const float4*)&bias[colb];
            f32x4 o = acc[mm][nn];
            o[0] += b4.x; o[1] += b4.y; o[2] += b4.z; o[3] += b4.w;
            __builtin_nontemporal_store(o, (f32x4*)&out[(size_t)row * N + colb]);
        }
}

extern "C" void kernel_launch(void* const* d_in, const int* in_sizes, int n_in,
                              void* d_out, int out_size, void* d_ws, size_t ws_size,
                              hipStream_t stream) {
    (void)in_sizes; (void)n_in; (void)out_size; (void)ws_size;

    const float* x  = (const float*)d_in[0];
    const float* Wq = (const float*)d_in[1];
    const float* bq = (const float*)d_in[2];
    const float* Wk = (const float*)d_in[3];
    const float* bk = (const float*)d_in[4];
    const float* Wv = (const float*)d_in[5];
    const float* bv = (const float*)d_in[6];
    const float* W1 = (const float*)d_in[7];
    const float* b1 = (const float*)d_in[8];
    const float* W2 = (const float*)d_in[9];
    const float* b2 = (const float*)d_in[10];

    char* p = (char*)d_ws;
    unsigned short* Wqkt  = (unsigned short*)p; p += (size_t)256 * 768 * 2;
    unsigned short* Gtb   = (unsigned short*)p; p += (size_t)256 * 768 * 2;
    float*          bprim = (float*)p;          p += (size_t)256 * 4;
    unsigned short* W2t   = (unsigned short*)p; p += (size_t)32000 * 256 * 2;
    unsigned short* Kall  = (unsigned short*)p; p += (size_t)49152 * 128 * 2;
    unsigned short* Pq    = (unsigned short*)p; p += (size_t)49152 * 128 * 2;
    unsigned short* hbar  = (unsigned short*)p; p += (size_t)4096 * 768 * 2;
    unsigned short* midb  = (unsigned short*)p; p += (size_t)4096 * 256 * 2;

    // one prep launch: Wqkt + Gt(fp32-direct) + b'
    prep_all<<<dim3(289), dim3(256), 0, stream>>>(Wk, Wq, Wqkt, Wv, W1, bv, b1, Gtb, bprim);

    // one pass over x: Kall = relu(x@Wk+bk), Pq = x@Wq
    proj_qk<<<dim3(49152 / 64), dim3(256), 0, stream>>>(x, Wqkt, bk, Kall, Pq);

    // scores (q fused) -> softmax -> hbar; W2 transpose rides along
    scores_plus_w2t<<<dim3(1024 + 8000), dim3(256), 0, stream>>>(
        x, Pq, bq, Kall, hbar, W2, W2t);

    // mid = relu(hbar @ Gt^T + b')
    gemm64<1, 1, 1><<<dim3(256 / 64, 4096 / 64), dim3(256), 0, stream>>>(
        hbar, Gtb, bprim, midb, 4096, 256, 768);

    // out = mid @ W2 + b2  (fp32)
    gemm_out<<<dim3(8000), dim3(256), 0, stream>>>(midb, W2t, b2, (float*)d_out);
}